// Round 2
// baseline (5185.945 us; speedup 1.0000x reference)
//
#include <hip/hip_runtime.h>
#include <hip/hip_bf16.h>

typedef __attribute__((ext_vector_type(8))) short short8;
typedef __attribute__((ext_vector_type(4))) float float4v;
typedef __attribute__((ext_vector_type(4))) unsigned int uint4v;
typedef unsigned short ushort_t;
typedef unsigned int uint_t;
typedef unsigned long long ull_t;

#define BB 64      // batch
#define SS 512     // seq len
#define HH 1024    // hidden
#define AA 128     // actions
#define NCG 128    // consumer (scan) WGs: 32 interleaved gate cols = 8 units each
#define RSLOTS 8   // gx ring depth (steps), power of 2

// ws layout (bytes)
#define XSW_BYTES   67108864ULL                  // [s][kk0..31][rg0..3][lane0..63][j0..7] bf16
#define WSW_BYTES   16777216ULL                  // [g0..255][kk0..63][lane][j] bf16
#define HALL_BYTES  67239936ULL                  // [slot 0..512][kk0..31][rg][lane][j] bf16 (slot s+1 = h_s)
#define XSW_OFF     0ULL
#define WSW_OFF     (XSW_OFF + XSW_BYTES)
#define HALL_OFF    (WSW_OFF + WSW_BYTES)
#define FLAGS_OFF   (HALL_OFF + HALL_BYTES)      // [0..127] scan flags, [128..255] producer flags
#define RING_OFF    (FLAGS_OFF + 4096ULL)        // gx ring: [slot][wg][tile][tid] u64 (4 bf16)
#define RING_BYTES  (RSLOTS * 128ULL * 2ULL * 256ULL * 8ULL)   // 4 MiB

#define MFMA __builtin_amdgcn_mfma_f32_16x16x32_bf16

__device__ __forceinline__ ushort_t f2bf(float f) {
    union { float f; uint_t u; } v; v.f = f;
    uint_t u = v.u;
    return (ushort_t)((u + 0x7fffu + ((u >> 16) & 1u)) >> 16);
}
__device__ __forceinline__ float bf2f(ushort_t u) {
    union { uint_t u; float f; } v; v.u = (uint_t)u << 16; return v.f;
}
__device__ __forceinline__ float fast_sigmoid(float x) {
    return __builtin_amdgcn_rcpf(1.0f + __expf(-x));
}
__device__ __forceinline__ float fast_tanh(float x) {
    return 1.0f - 2.0f * __builtin_amdgcn_rcpf(1.0f + __expf(2.0f * x));
}

// ---------------- init: flags (scan + producer), Hall[0], output dummy blocks ----------------
__global__ void k_init(uint_t* __restrict__ flags, ushort_t* __restrict__ hall,
                       float* __restrict__ out) {
    int i = blockIdx.x * 256 + threadIdx.x;          // 32768 threads
    if (i < 256) flags[i] = 0u;
    ((uint_t*)hall)[i] = 0u;                          // 65536 ushorts = 32768 uints (slot 0)
    out[i] = 0.0f;                                    // dummy block 0
    out[32768 + (size_t)BB * SS * AA + i] = 0.0f;     // dummy block 2
}

// ---------------- x_emb gather + bf16 + A-fragment swizzle ----------------
__global__ void k_prep_x(const float* __restrict__ embed, const int* __restrict__ x,
                         ushort_t* __restrict__ xsw) {
    int t = blockIdx.x * 256 + threadIdx.x;          // 4,194,304 threads = [s][kk][rg][lane]
    int lane = t & 63;
    int rg   = (t >> 6) & 3;
    int kk   = (t >> 8) & 31;
    int s    = t >> 13;
    int b  = rg * 16 + (lane & 15);
    int k0 = kk * 32 + (lane >> 4) * 8;
    int tok = x[b * SS + s];
    const float* src = embed + (size_t)tok * HH + k0;
    float4v v0 = *(const float4v*)src;
    float4v v1 = *(const float4v*)(src + 4);
    uint_t p0 = (uint_t)f2bf(v0[0]) | ((uint_t)f2bf(v0[1]) << 16);
    uint_t p1 = (uint_t)f2bf(v0[2]) | ((uint_t)f2bf(v0[3]) << 16);
    uint_t p2 = (uint_t)f2bf(v1[0]) | ((uint_t)f2bf(v1[1]) << 16);
    uint_t p3 = (uint_t)f2bf(v1[2]) | ((uint_t)f2bf(v1[3]) << 16);
    uint4v pk = {p0, p1, p2, p3};
    ((uint4v*)xsw)[t] = pk;
}

// ---------------- [Wi;Wh] -> bf16, gate-interleaved cols, B-fragment swizzle ----------------
__global__ void k_prep_w(const float* __restrict__ Wi, const float* __restrict__ Wh,
                         ushort_t* __restrict__ wsw) {
    int t = blockIdx.x * 256 + threadIdx.x;          // 8,388,608 threads = [k][q][u]
    int u = t & 1023;
    int q = (t >> 10) & 3;
    int k = t >> 12;                                 // 0..2047
    float v = (k < 1024) ? Wi[(size_t)k * 4096 + q * 1024 + u]
                         : Wh[(size_t)(k - 1024) * 4096 + q * 1024 + u];
    int g = u >> 2, du = u & 3;
    int c = du * 4 + q;                              // col-in-slice 0..15
    int kk = k >> 5, quad = (k >> 3) & 3, j = k & 7;
    int lane = quad * 16 + c;
    wsw[(((size_t)g * 64 + kk) * 64 + lane) * 8 + j] = f2bf(v);
}

// ---------------- persistent LSTM: 128 producer WGs (gx = x@Wi + bh, ring-buffered
//                  RSLOTS steps ahead) + 128 consumer WGs (h-recurrence only) ----------------
__global__ void __launch_bounds__(256)
k_lstm2(const ushort_t* __restrict__ xsw, const ushort_t* __restrict__ wsw,
        ushort_t* hall, const float* __restrict__ bh, uint_t* flags, ull_t* ring) {
    // 64 KiB weights + 22 KiB pad -> 86 KiB LDS forces exactly 1 WG/CU (co-residency of all 256 WGs)
    __shared__ ushort_t wlds[2 * 32 * 64 * 8 + 11264];
    const int tid  = threadIdx.x;
    const int lane = tid & 63;
    const int rg   = tid >> 6;                       // wave id = batch row-group
    const bool producer = (blockIdx.x >= NCG);
    const int  wg = producer ? (blockIdx.x - NCG) : blockIdx.x;   // 0..127 both roles

    {   // stage weight slices for groups {2wg, 2wg+1}: producer = Wi rows (kk 0..31),
        // consumer = Wh rows (kk 32..63). LDS layout: [tile][kk'0..31][lane][j]
        const int kkoff = producer ? 0 : 32;
        const uint4v* s0 = (const uint4v*)(wsw + ((size_t)(2 * wg)     * 64 + kkoff) * 512);
        const uint4v* s1 = (const uint4v*)(wsw + ((size_t)(2 * wg + 1) * 64 + kkoff) * 512);
        uint4v* dst = (uint4v*)wlds;
        for (int i = tid; i < 2048; i += 256) { dst[i] = s0[i]; dst[2048 + i] = s1[i]; }
    }
    __syncthreads();

    const int c_idx = lane & 15;
    const int q  = c_idx & 3;                        // gate (i,f,g,o)
    const int du = c_idx >> 2;                       // unit-within-group
    const int quad = lane >> 4;
    const short8* wl = (const short8*)wlds + lane;

    if (producer) {
        // ---- gx producer: runs ahead of the scan, throttled by consumer progress ----
        const float bhv0 = bh[q * 1024 + (2 * wg)     * 4 + du];
        const float bhv1 = bh[q * 1024 + (2 * wg + 1) * 4 + du];
        const short8* xbase = (const short8*)xsw;
        for (int s = 0; s < SS; ++s) {
            float4v a00 = {bhv0, bhv0, bhv0, bhv0};
            float4v a01 = {0.f, 0.f, 0.f, 0.f};
            float4v a10 = {bhv1, bhv1, bhv1, bhv1};
            float4v a11 = {0.f, 0.f, 0.f, 0.f};
            const short8* xp = xbase + (((size_t)s * 32) * 4 + rg) * 64 + lane;
            #pragma unroll
            for (int kk = 0; kk < 32; kk += 2) {
                short8 f0 = xp[(kk + 0) * 256];
                short8 f1 = xp[(kk + 1) * 256];
                a00 = MFMA(f0, wl[(kk + 0) * 64], a00, 0, 0, 0);
                a10 = MFMA(f0, wl[(32 + kk + 0) * 64], a10, 0, 0, 0);
                a01 = MFMA(f1, wl[(kk + 1) * 64], a01, 0, 0, 0);
                a11 = MFMA(f1, wl[(32 + kk + 1) * 64], a11, 0, 0, 0);
            }
            float4v g0 = a00 + a01;
            float4v g1 = a10 + a11;
            // backpressure: don't overwrite ring slot until consumer finished step s-RSLOTS
            {
                int need = s - (RSLOTS - 1);
                if (need > 0) {
                    while ((int)__hip_atomic_load(&flags[wg], __ATOMIC_RELAXED,
                                                  __HIP_MEMORY_SCOPE_AGENT) < need)
                        __builtin_amdgcn_s_sleep(2);
                }
            }
            ull_t* rp = ring + ((size_t)(s & (RSLOTS - 1)) * 128 + wg) * 512 + tid;
            uint_t d0 = (uint_t)f2bf(g0[0]) | ((uint_t)f2bf(g0[1]) << 16);
            uint_t d1 = (uint_t)f2bf(g0[2]) | ((uint_t)f2bf(g0[3]) << 16);
            __hip_atomic_store(&rp[0], (ull_t)d0 | ((ull_t)d1 << 32),
                               __ATOMIC_RELAXED, __HIP_MEMORY_SCOPE_AGENT);
            uint_t e0 = (uint_t)f2bf(g1[0]) | ((uint_t)f2bf(g1[1]) << 16);
            uint_t e1 = (uint_t)f2bf(g1[2]) | ((uint_t)f2bf(g1[3]) << 16);
            __hip_atomic_store(&rp[256], (ull_t)e0 | ((ull_t)e1 << 32),
                               __ATOMIC_RELAXED, __HIP_MEMORY_SCOPE_AGENT);
            __syncthreads();                         // drains vmcnt(0) for ALL waves (HW release)
            if (tid == 0)
                __hip_atomic_store(&flags[128 + wg], (uint_t)(s + 1),
                                   __ATOMIC_RELAXED, __HIP_MEMORY_SCOPE_AGENT);
        }
        return;
    }

    // ---- consumer: sequential h-recurrence, 2 output tiles (32 cols) per WG ----
    uint_t* hall32 = (uint_t*)hall;
    const short8* hbase = (const short8*)hall;
    float cst[2][4];
    #pragma unroll
    for (int t = 0; t < 2; ++t)
        #pragma unroll
        for (int r = 0; r < 4; ++r) cst[t][r] = 0.f;

    for (int s = 0; s < SS; ++s) {
        // wait: all 128 scan WGs posted h(s-1); own producer posted gx(s)
        {
            const uint_t* addr = (tid < 128) ? &flags[tid] : &flags[128 + wg];
            const uint_t need  = (tid < 128) ? (uint_t)s : (uint_t)(s + 1);
            bool ok;
            do {
                uint_t f = __hip_atomic_load(addr, __ATOMIC_RELAXED,
                                             __HIP_MEMORY_SCOPE_AGENT);
                ok = (f >= need);
            } while (!__syncthreads_and(ok));
            asm volatile("" ::: "memory");   // no fence: data traveled via sc1 (LLC)
        }

        // gx (4 bf16 per tile); ring slots are reused within the run -> sc1 loads (bypass L2)
        const ull_t* rp = ring + ((size_t)(s & (RSLOTS - 1)) * 128 + wg) * 512 + tid;
        ull_t gx0 = __hip_atomic_load(&rp[0],   __ATOMIC_RELAXED, __HIP_MEMORY_SCOPE_AGENT);
        ull_t gx1 = __hip_atomic_load(&rp[256], __ATOMIC_RELAXED, __HIP_MEMORY_SCOPE_AGENT);

        float4v a00 = {0.f, 0.f, 0.f, 0.f};
        float4v a01 = {0.f, 0.f, 0.f, 0.f};
        float4v a10 = {0.f, 0.f, 0.f, 0.f};
        float4v a11 = {0.f, 0.f, 0.f, 0.f};
        const short8* hp = hbase + (((size_t)s * 32) * 4 + rg) * 64 + lane;
        #pragma unroll
        for (int kk = 0; kk < 32; kk += 2) {
            short8 f0 = hp[(kk + 0) * 256];
            short8 f1 = hp[(kk + 1) * 256];
            a00 = MFMA(f0, wl[(kk + 0) * 64], a00, 0, 0, 0);
            a10 = MFMA(f0, wl[(32 + kk + 0) * 64], a10, 0, 0, 0);
            a01 = MFMA(f1, wl[(kk + 1) * 64], a01, 0, 0, 0);
            a11 = MFMA(f1, wl[(32 + kk + 1) * 64], a11, 0, 0, 0);
        }
        float4v acc0 = a00 + a01;
        float4v acc1 = a10 + a11;
        acc0[0] += bf2f((ushort_t)gx0);
        acc0[1] += bf2f((ushort_t)(gx0 >> 16));
        acc0[2] += bf2f((ushort_t)(gx0 >> 32));
        acc0[3] += bf2f((ushort_t)(gx0 >> 48));
        acc1[0] += bf2f((ushort_t)gx1);
        acc1[1] += bf2f((ushort_t)(gx1 >> 16));
        acc1[2] += bf2f((ushort_t)(gx1 >> 32));
        acc1[3] += bf2f((ushort_t)(gx1 >> 48));

        // elementwise LSTM update per tile: activate own gate, shuffle activated
        float hv[2][4];
        #pragma unroll
        for (int t = 0; t < 2; ++t) {
            #pragma unroll
            for (int r = 0; r < 4; ++r) {
                float own = t ? acc1[r] : acc0[r];
                float a = (q == 2) ? fast_tanh(own) : fast_sigmoid(own);
                float x1 = __shfl_xor(a, 1);
                float x2 = __shfl_xor(a, 2);
                float x3 = __shfl_xor(a, 3);
                float gi, gf, gg, go;
                if      (q == 0) { gi = a;  gf = x1; gg = x2; go = x3; }
                else if (q == 1) { gi = x1; gf = a;  gg = x3; go = x2; }
                else if (q == 2) { gi = x2; gf = x3; gg = a;  go = x1; }
                else             { gi = x3; gf = x2; gg = x1; go = a;  }
                float cv = gf * cst[t][r] + gi * gg;
                cst[t][r] = cv;
                hv[t][r] = go * fast_tanh(cv);
            }
        }

        // pack (even u, odd u) bf16 pair -> one dword sc1 store to LLC, per tile
        #pragma unroll
        for (int t = 0; t < 2; ++t) {
            float p0 = __shfl_xor(hv[t][0], 4);
            float p1 = __shfl_xor(hv[t][1], 4);
            float p2 = __shfl_xor(hv[t][2], 4);
            float p3 = __shfl_xor(hv[t][3], 4);
            if (q == 0 && (du & 1) == 0) {
                int u = (2 * wg + t) * 4 + du;
                int kk_h = u >> 5, quad_h = (u & 31) >> 3, j_h = u & 7;   // j_h even
                size_t base = (((size_t)(s + 1) * 32 + kk_h) * 4 + rg) * 64;
                float pv[4] = {p0, p1, p2, p3};
                #pragma unroll
                for (int r = 0; r < 4; ++r) {
                    uint_t packed = (uint_t)f2bf(hv[t][r]) | ((uint_t)f2bf(pv[r]) << 16);
                    int lane_h = quad_h * 16 + quad * 4 + r;
                    size_t idx = ((base + (size_t)lane_h) * 8 + j_h) >> 1;
                    __hip_atomic_store(&hall32[idx], packed, __ATOMIC_RELAXED,
                                       __HIP_MEMORY_SCOPE_AGENT);
                }
            }
        }
        __syncthreads();                             // drain vmcnt(0) for ALL waves
        if (tid == 0)
            __hip_atomic_store(&flags[wg], (uint_t)(s + 1), __ATOMIC_RELAXED,
                               __HIP_MEMORY_SCOPE_AGENT);
    }
}

// ---------------- head GEMM: logits[b][s][:] = h_s @ Wo + bo ----------------
__global__ void __launch_bounds__(256)
k_head(const ushort_t* __restrict__ hall, const float* __restrict__ Wo,
       const float* __restrict__ bo, float* __restrict__ out) {
    __shared__ ushort_t wlds[32 * 2 * 64 * 8];       // 64 KiB: [kk][nt][lane][j]
    const int wg = blockIdx.x;                       // 512 WGs: cg(4) x sg(128)
    const int cg = wg & 3, sg = wg >> 2;
    const int tid = threadIdx.x, lane = tid & 63, rg = tid >> 6;
    const int col0 = cg * 32;

    for (int i = tid; i < 32768; i += 256) {         // [k][col] -> B-frag swizzle
        int k = i >> 5;
        int col = i & 31;
        float v = Wo[(size_t)k * AA + col0 + col];
        int kk = k >> 5, quad = (k >> 3) & 3, j = k & 7;
        int nt = col >> 4, cl = col & 15;
        wlds[(((kk * 2 + nt) * 64) + quad * 16 + cl) * 8 + j] = f2bf(v);
    }
    __syncthreads();

    const int cl = lane & 15, quad = lane >> 4;
    const float bo0 = bo[col0 + cl];
    const float bo1 = bo[col0 + 16 + cl];
    const short8* wl = (const short8*)wlds + lane;

    for (int si = 0; si < 4; ++si) {
        int s = sg * 4 + si;
        float4v a0 = {bo0, bo0, bo0, bo0};
        float4v a1 = {bo1, bo1, bo1, bo1};
        const short8* hp = (const short8*)hall + (((size_t)(s + 1) * 32) * 4 + rg) * 64 + lane;
        #pragma unroll 8
        for (int kk = 0; kk < 32; ++kk) {
            short8 a = hp[kk * 256];
            a0 = MFMA(a, wl[(kk * 2 + 0) * 64], a0, 0, 0, 0);
            a1 = MFMA(a, wl[(kk * 2 + 1) * 64], a1, 0, 0, 0);
        }
        #pragma unroll
        for (int r = 0; r < 4; ++r) {
            int b = rg * 16 + quad * 4 + r;
            size_t o = 32768 + ((size_t)b * SS + s) * AA;
            out[o + col0 + cl]      = a0[r];
            out[o + col0 + 16 + cl] = a1[r];
        }
    }
}

extern "C" void kernel_launch(void* const* d_in, const int* in_sizes, int n_in,
                              void* d_out, int out_size, void* d_ws, size_t ws_size,
                              hipStream_t stream) {
    const float* embed = (const float*)d_in[0];
    const float* Wi    = (const float*)d_in[1];
    const float* Wh    = (const float*)d_in[2];
    const float* bh    = (const float*)d_in[3];
    const float* Wo    = (const float*)d_in[4];
    const float* bo    = (const float*)d_in[5];
    const int*   x     = (const int*)d_in[6];
    float* out = (float*)d_out;
    unsigned char* ws = (unsigned char*)d_ws;

    ushort_t* xsw   = (ushort_t*)(ws + XSW_OFF);
    ushort_t* wsw   = (ushort_t*)(ws + WSW_OFF);
    ushort_t* hall  = (ushort_t*)(ws + HALL_OFF);
    uint_t*   flags = (uint_t*)(ws + FLAGS_OFF);
    ull_t*    ring  = (ull_t*)(ws + RING_OFF);

    k_init  <<<128,   256, 0, stream>>>(flags, hall, out);
    k_prep_x<<<16384, 256, 0, stream>>>(embed, x, xsw);
    k_prep_w<<<32768, 256, 0, stream>>>(Wi, Wh, wsw);
    k_lstm2 <<<256,   256, 0, stream>>>(xsw, wsw, hall, bh, flags, ring);
    k_head  <<<512,   256, 0, stream>>>(hall, Wo, bo, out);
}

// Round 3
// 5105.297 us; speedup vs baseline: 1.0158x; 1.0158x over previous
//
#include <hip/hip_runtime.h>
#include <hip/hip_bf16.h>

typedef __attribute__((ext_vector_type(8))) short short8;
typedef __attribute__((ext_vector_type(4))) float float4v;
typedef __attribute__((ext_vector_type(4))) unsigned int uint4v;
typedef unsigned short ushort_t;
typedef unsigned int uint_t;

#define BB 64      // batch
#define SS 512     // seq len
#define HH 1024    // hidden
#define AA 128     // actions
#define NWG 256    // recurrent workgroups (each owns 16 interleaved gate cols = 4 units)

// ws layout (bytes)
#define XSW_BYTES   67108864ULL                  // [s][kk0..31][rg0..3][lane0..63][j0..7] bf16
#define WSW_BYTES   16777216ULL                  // [g0..255][kk0..63][lane][j] bf16
#define HALL_BYTES  67239936ULL                  // [slot 0..512][kk0..31][rg][lane][j] bf16 (slot s+1 = h_s)
#define XSW_OFF     0ULL
#define WSW_OFF     (XSW_OFF + XSW_BYTES)
#define HALL_OFF    (WSW_OFF + WSW_BYTES)
#define FLAGS_OFF   (HALL_OFF + HALL_BYTES)

#define MFMA __builtin_amdgcn_mfma_f32_16x16x32_bf16

__device__ __forceinline__ ushort_t f2bf(float f) {
    union { float f; uint_t u; } v; v.f = f;
    uint_t u = v.u;
    return (ushort_t)((u + 0x7fffu + ((u >> 16) & 1u)) >> 16);
}

__device__ __forceinline__ float fast_sigmoid(float x) {
    return __builtin_amdgcn_rcpf(1.0f + __expf(-x));
}
__device__ __forceinline__ float fast_tanh(float x) {
    return 1.0f - 2.0f * __builtin_amdgcn_rcpf(1.0f + __expf(2.0f * x));
}

// ---------------- init: flags, Hall[0] (h_{-1}=0), output dummy blocks ----------------
__global__ void k_init(uint_t* __restrict__ flags, ushort_t* __restrict__ hall,
                       float* __restrict__ out) {
    int i = blockIdx.x * 256 + threadIdx.x;          // 32768 threads
    if (i < NWG) flags[i] = 0u;
    ((uint_t*)hall)[i] = 0u;                          // 65536 ushorts = 32768 uints (slot 0)
    out[i] = 0.0f;                                    // dummy block 0
    out[32768 + (size_t)BB * SS * AA + i] = 0.0f;     // dummy block 2
}

// ---------------- x_emb gather + bf16 + A-fragment swizzle ----------------
__global__ void k_prep_x(const float* __restrict__ embed, const int* __restrict__ x,
                         ushort_t* __restrict__ xsw) {
    int t = blockIdx.x * 256 + threadIdx.x;          // 4,194,304 threads = [s][kk][rg][lane]
    int lane = t & 63;
    int rg   = (t >> 6) & 3;
    int kk   = (t >> 8) & 31;
    int s    = t >> 13;
    int b  = rg * 16 + (lane & 15);
    int k0 = kk * 32 + (lane >> 4) * 8;
    int tok = x[b * SS + s];
    const float* src = embed + (size_t)tok * HH + k0;
    float4v v0 = *(const float4v*)src;
    float4v v1 = *(const float4v*)(src + 4);
    uint_t p0 = (uint_t)f2bf(v0[0]) | ((uint_t)f2bf(v0[1]) << 16);
    uint_t p1 = (uint_t)f2bf(v0[2]) | ((uint_t)f2bf(v0[3]) << 16);
    uint_t p2 = (uint_t)f2bf(v1[0]) | ((uint_t)f2bf(v1[1]) << 16);
    uint_t p3 = (uint_t)f2bf(v1[2]) | ((uint_t)f2bf(v1[3]) << 16);
    uint4v pk = {p0, p1, p2, p3};
    ((uint4v*)xsw)[t] = pk;
}

// ---------------- [Wi;Wh] -> bf16, gate-interleaved cols, B-fragment swizzle ----------------
__global__ void k_prep_w(const float* __restrict__ Wi, const float* __restrict__ Wh,
                         ushort_t* __restrict__ wsw) {
    int t = blockIdx.x * 256 + threadIdx.x;          // 8,388,608 threads = [k][q][u]
    int u = t & 1023;
    int q = (t >> 10) & 3;
    int k = t >> 12;                                 // 0..2047
    float v = (k < 1024) ? Wi[(size_t)k * 4096 + q * 1024 + u]
                         : Wh[(size_t)(k - 1024) * 4096 + q * 1024 + u];
    int g = u >> 2, du = u & 3;
    int c = du * 4 + q;                              // col-in-slice 0..15
    int kk = k >> 5, quad = (k >> 3) & 3, j = k & 7;
    int lane = quad * 16 + c;
    wsw[(((size_t)g * 64 + kk) * 64 + lane) * 8 + j] = f2bf(v);
}

// ---------------- persistent sequential LSTM scan (re-scheduled body) ----------------
// body(s):  xA(s) [hides drain of slot-s stores from body(s-1)]
//           __syncthreads [drains] -> post flag=s
//           xB(s) [hides flag visibility; flag pre-loads in flight]
//           poll flags>=s (per-wave __all, no barrier)
//           h(s) MFMAs -> elementwise -> issue slot-(s+1) stores (NO wait)
__global__ void __launch_bounds__(256)
k_lstm(const ushort_t* __restrict__ xsw, const ushort_t* __restrict__ wsw,
       ushort_t* hall, const float* __restrict__ bh, uint_t* flags) {
    // 64 KiB weights + 20 KiB pad -> forces exactly 1 WG/CU (co-residency of all 256 WGs)
    __shared__ ushort_t wlds[64 * 64 * 8 + 10240];
    const int g    = blockIdx.x;
    const int tid  = threadIdx.x;
    const int lane = tid & 63;
    const int rg   = tid >> 6;                       // wave id = batch row-group

    {   // stage weight slice (coalesced 16B/lane)
        const uint4v* src = (const uint4v*)(wsw + (size_t)g * 64 * 64 * 8);
        uint4v* dst = (uint4v*)wlds;
        for (int i = tid; i < 4096; i += 256) dst[i] = src[i];
    }
    __syncthreads();

    const int c_idx = lane & 15;
    const int q  = c_idx & 3;
    const int du = c_idx >> 2;
    const int quad = lane >> 4;
    const int u = g * 4 + du;                        // hidden unit this lane group owns
    const float bhv = bh[q * 1024 + u];

    // h write coords (lanes with q==0 && du even store packed pairs)
    const int kk_h = u >> 5;
    const int quad_h = (u & 31) >> 3;
    const int j_h = u & 7;                            // even for storing lanes
    uint_t* hall32 = (uint_t*)hall;
    const short8* xbase = (const short8*)xsw;
    const short8* hbase = (const short8*)hall;
    const short8* wl = (const short8*)wlds + lane;

    float cst0 = 0.f, cst1 = 0.f, cst2 = 0.f, cst3 = 0.f;  // c-state, 4 batch rows

    for (int s = 0; s < SS; ++s) {
        float4v ac0 = {bhv, bhv, bhv, bhv};
        float4v ac1 = {0.f, 0.f, 0.f, 0.f};
        float4v ac2 = {0.f, 0.f, 0.f, 0.f};
        float4v ac3 = {0.f, 0.f, 0.f, 0.f};

        const short8* xp = xbase + (((size_t)s * 32) * 4 + rg) * 64 + lane;

        // ---- xA: first half of the x-part; its loads + the pending slot-s
        //      stores from the previous iteration drain together at the barrier ----
        #pragma unroll
        for (int kk = 0; kk < 16; kk += 4) {
            short8 a0 = xp[(kk + 0) * 256];
            short8 a1 = xp[(kk + 1) * 256];
            short8 a2 = xp[(kk + 2) * 256];
            short8 a3 = xp[(kk + 3) * 256];
            ac0 = MFMA(a0, wl[(kk + 0) * 64], ac0, 0, 0, 0);
            ac1 = MFMA(a1, wl[(kk + 1) * 64], ac1, 0, 0, 0);
            ac2 = MFMA(a2, wl[(kk + 2) * 64], ac2, 0, 0, 0);
            ac3 = MFMA(a3, wl[(kk + 3) * 64], ac3, 0, 0, 0);
        }

        // ---- barrier drains all waves' slot-s stores (HW release), then certify ----
        __syncthreads();
        if (tid == 0)
            __hip_atomic_store(&flags[g], (uint_t)s, __ATOMIC_RELAXED,
                               __HIP_MEMORY_SCOPE_AGENT);

        // ---- pre-issue flag reads (monotone: stale >= s is a valid pass) ----
        uint_t f0 = __hip_atomic_load(&flags[lane],       __ATOMIC_RELAXED, __HIP_MEMORY_SCOPE_AGENT);
        uint_t f1 = __hip_atomic_load(&flags[64 + lane],  __ATOMIC_RELAXED, __HIP_MEMORY_SCOPE_AGENT);
        uint_t f2 = __hip_atomic_load(&flags[128 + lane], __ATOMIC_RELAXED, __HIP_MEMORY_SCOPE_AGENT);
        uint_t f3 = __hip_atomic_load(&flags[192 + lane], __ATOMIC_RELAXED, __HIP_MEMORY_SCOPE_AGENT);

        // ---- xB: second half of the x-part; hides own-post visibility + flag flight ----
        #pragma unroll
        for (int kk = 16; kk < 32; kk += 4) {
            short8 a0 = xp[(kk + 0) * 256];
            short8 a1 = xp[(kk + 1) * 256];
            short8 a2 = xp[(kk + 2) * 256];
            short8 a3 = xp[(kk + 3) * 256];
            ac0 = MFMA(a0, wl[(kk + 0) * 64], ac0, 0, 0, 0);
            ac1 = MFMA(a1, wl[(kk + 1) * 64], ac1, 0, 0, 0);
            ac2 = MFMA(a2, wl[(kk + 2) * 64], ac2, 0, 0, 0);
            ac3 = MFMA(a3, wl[(kk + 3) * 64], ac3, 0, 0, 0);
        }

        // ---- per-wave poll: each wave independently verifies all 256 flags ----
        {
            const uint_t sn = (uint_t)s;
            bool ok = (f0 >= sn) & (f1 >= sn) & (f2 >= sn) & (f3 >= sn);
            while (!__all(ok)) {
                f0 = __hip_atomic_load(&flags[lane],       __ATOMIC_RELAXED, __HIP_MEMORY_SCOPE_AGENT);
                f1 = __hip_atomic_load(&flags[64 + lane],  __ATOMIC_RELAXED, __HIP_MEMORY_SCOPE_AGENT);
                f2 = __hip_atomic_load(&flags[128 + lane], __ATOMIC_RELAXED, __HIP_MEMORY_SCOPE_AGENT);
                f3 = __hip_atomic_load(&flags[192 + lane], __ATOMIC_RELAXED, __HIP_MEMORY_SCOPE_AGENT);
                ok = (f0 >= sn) & (f1 >= sn) & (f2 >= sn) & (f3 >= sn);
            }
            asm volatile("" ::: "memory");   // no fence: h-writes traveled via sc1 (LLC); slot write-once
        }

        // ---- h-part (normal cached loads; slot s is write-once, no stale copies) ----
        const short8* hp = hbase + (((size_t)s * 32) * 4 + rg) * 64 + lane;
        #pragma unroll
        for (int kk = 0; kk < 32; kk += 4) {
            short8 a0 = hp[(kk + 0) * 256];
            short8 a1 = hp[(kk + 1) * 256];
            short8 a2 = hp[(kk + 2) * 256];
            short8 a3 = hp[(kk + 3) * 256];
            ac0 = MFMA(a0, wl[(32 + kk + 0) * 64], ac0, 0, 0, 0);
            ac1 = MFMA(a1, wl[(32 + kk + 1) * 64], ac1, 0, 0, 0);
            ac2 = MFMA(a2, wl[(32 + kk + 2) * 64], ac2, 0, 0, 0);
            ac3 = MFMA(a3, wl[(32 + kk + 3) * 64], ac3, 0, 0, 0);
        }
        float4v acc = (ac0 + ac1) + (ac2 + ac3);

        // ---- elementwise LSTM update: activate own gate, then shuffle activated ----
        float hv[4];
        #pragma unroll
        for (int r = 0; r < 4; ++r) {
            float own = acc[r];
            float a = (q == 2) ? fast_tanh(own) : fast_sigmoid(own);
            float x1 = __shfl_xor(a, 1);
            float x2 = __shfl_xor(a, 2);
            float x3 = __shfl_xor(a, 3);
            float gi, gf, gg, go;
            if      (q == 0) { gi = a;  gf = x1; gg = x2; go = x3; }
            else if (q == 1) { gi = x1; gf = a;  gg = x3; go = x2; }
            else if (q == 2) { gi = x2; gf = x3; gg = a;  go = x1; }
            else             { gi = x3; gf = x2; gg = x1; go = a;  }
            float cv = (r == 0 ? cst0 : r == 1 ? cst1 : r == 2 ? cst2 : cst3);
            cv = gf * cv + gi * gg;
            if (r == 0) cst0 = cv; else if (r == 1) cst1 = cv;
            else if (r == 2) cst2 = cv; else cst3 = cv;
            hv[r] = go * fast_tanh(cv);
        }

        // ---- pack (even u, odd u) bf16 pair -> dword sc1 stores; NO drain here:
        //      next iteration's xA + barrier hide the drain before the flag post ----
        float pv0 = __shfl_xor(hv[0], 4);
        float pv1 = __shfl_xor(hv[1], 4);
        float pv2 = __shfl_xor(hv[2], 4);
        float pv3 = __shfl_xor(hv[3], 4);
        if (q == 0 && (du & 1) == 0) {
            float pv[4] = {pv0, pv1, pv2, pv3};
            size_t base = (((size_t)(s + 1) * 32 + kk_h) * 4 + rg) * 64;
            #pragma unroll
            for (int r = 0; r < 4; ++r) {
                uint_t packed = (uint_t)f2bf(hv[r]) | ((uint_t)f2bf(pv[r]) << 16);
                int lane_h = quad_h * 16 + quad * 4 + r;
                size_t idx = ((base + (size_t)lane_h) * 8 + j_h) >> 1;
                __hip_atomic_store(&hall32[idx], packed, __ATOMIC_RELAXED,
                                   __HIP_MEMORY_SCOPE_AGENT);
            }
        }
        // fall through to next iteration: xA -> __syncthreads (drain) -> post flag=s+1
    }
    // final slot-512 stores drain at kernel end, before k_head launches
}

// ---------------- head GEMM: logits[b][s][:] = h_s @ Wo + bo ----------------
__global__ void __launch_bounds__(256)
k_head(const ushort_t* __restrict__ hall, const float* __restrict__ Wo,
       const float* __restrict__ bo, float* __restrict__ out) {
    __shared__ ushort_t wlds[32 * 2 * 64 * 8];       // 64 KiB: [kk][nt][lane][j]
    const int wg = blockIdx.x;                       // 512 WGs: cg(4) x sg(128)
    const int cg = wg & 3, sg = wg >> 2;
    const int tid = threadIdx.x, lane = tid & 63, rg = tid >> 6;
    const int col0 = cg * 32;

    for (int i = tid; i < 32768; i += 256) {         // [k][col] -> B-frag swizzle
        int k = i >> 5;
        int col = i & 31;
        float v = Wo[(size_t)k * AA + col0 + col];
        int kk = k >> 5, quad = (k >> 3) & 3, j = k & 7;
        int nt = col >> 4, cl = col & 15;
        wlds[(((kk * 2 + nt) * 64) + quad * 16 + cl) * 8 + j] = f2bf(v);
    }
    __syncthreads();

    const int cl = lane & 15, quad = lane >> 4;
    const float bo0 = bo[col0 + cl];
    const float bo1 = bo[col0 + 16 + cl];
    const short8* wl = (const short8*)wlds + lane;

    for (int si = 0; si < 4; ++si) {
        int s = sg * 4 + si;
        float4v a0 = {bo0, bo0, bo0, bo0};
        float4v a1 = {bo1, bo1, bo1, bo1};
        const short8* hp = (const short8*)hall + (((size_t)(s + 1) * 32) * 4 + rg) * 64 + lane;
        #pragma unroll 8
        for (int kk = 0; kk < 32; ++kk) {
            short8 a = hp[kk * 256];
            a0 = MFMA(a, wl[(kk * 2 + 0) * 64], a0, 0, 0, 0);
            a1 = MFMA(a, wl[(kk * 2 + 1) * 64], a1, 0, 0, 0);
        }
        #pragma unroll
        for (int r = 0; r < 4; ++r) {
            int b = rg * 16 + quad * 4 + r;
            size_t o = 32768 + ((size_t)b * SS + s) * AA;
            out[o + col0 + cl]      = a0[r];
            out[o + col0 + 16 + cl] = a1[r];
        }
    }
}

extern "C" void kernel_launch(void* const* d_in, const int* in_sizes, int n_in,
                              void* d_out, int out_size, void* d_ws, size_t ws_size,
                              hipStream_t stream) {
    const float* embed = (const float*)d_in[0];
    const float* Wi    = (const float*)d_in[1];
    const float* Wh    = (const float*)d_in[2];
    const float* bh    = (const float*)d_in[3];
    const float* Wo    = (const float*)d_in[4];
    const float* bo    = (const float*)d_in[5];
    const int*   x     = (const int*)d_in[6];
    float* out = (float*)d_out;
    unsigned char* ws = (unsigned char*)d_ws;

    ushort_t* xsw  = (ushort_t*)(ws + XSW_OFF);
    ushort_t* wsw  = (ushort_t*)(ws + WSW_OFF);
    ushort_t* hall = (ushort_t*)(ws + HALL_OFF);
    uint_t*   flags = (uint_t*)(ws + FLAGS_OFF);

    k_init  <<<128,   256, 0, stream>>>(flags, hall, out);
    k_prep_x<<<16384, 256, 0, stream>>>(embed, x, xsw);
    k_prep_w<<<32768, 256, 0, stream>>>(Wi, Wh, wsw);
    k_lstm  <<<NWG,   256, 0, stream>>>(xsw, wsw, hall, bh, flags);
    k_head  <<<512,   256, 0, stream>>>(hall, Wo, bo, out);
}

// Round 4
// 4437.859 us; speedup vs baseline: 1.1686x; 1.1504x over previous
//
#include <hip/hip_runtime.h>
#include <hip/hip_bf16.h>

typedef __attribute__((ext_vector_type(8))) short short8;
typedef __attribute__((ext_vector_type(4))) float float4v;
typedef __attribute__((ext_vector_type(4))) unsigned int uint4v;
typedef unsigned short ushort_t;
typedef unsigned int uint_t;

#define BB 64      // batch
#define SS 512     // seq len
#define HH 1024    // hidden
#define AA 128     // actions
#define NSL 256    // weight slices (16 gate-interleaved cols each) -- prep layout unchanged
#define NWG 128    // recurrent workgroups: each owns 2 slices = 32 cols = 8 units

// ws layout (bytes)
#define XSW_BYTES   67108864ULL                  // [s][kk0..31][rg0..3][lane0..63][j0..7] bf16
#define WSW_BYTES   16777216ULL                  // [g0..255][kk0..63][lane][j] bf16
#define HALL_BYTES  67239936ULL                  // [slot 0..512][kk0..31][rg][lane][j] bf16 (slot s+1 = h_s)
#define XSW_OFF     0ULL
#define WSW_OFF     (XSW_OFF + XSW_BYTES)
#define HALL_OFF    (WSW_OFF + WSW_BYTES)
#define FLAGS_OFF   (HALL_OFF + HALL_BYTES)

#define MFMA __builtin_amdgcn_mfma_f32_16x16x32_bf16

__device__ __forceinline__ ushort_t f2bf(float f) {
    union { float f; uint_t u; } v; v.f = f;
    uint_t u = v.u;
    return (ushort_t)((u + 0x7fffu + ((u >> 16) & 1u)) >> 16);
}

__device__ __forceinline__ float fast_sigmoid(float x) {
    return __builtin_amdgcn_rcpf(1.0f + __expf(-x));
}
__device__ __forceinline__ float fast_tanh(float x) {
    return 1.0f - 2.0f * __builtin_amdgcn_rcpf(1.0f + __expf(2.0f * x));
}

// ---------------- init: flags, Hall[0] (h_{-1}=0), output dummy blocks ----------------
__global__ void k_init(uint_t* __restrict__ flags, ushort_t* __restrict__ hall,
                       float* __restrict__ out) {
    int i = blockIdx.x * 256 + threadIdx.x;          // 32768 threads
    if (i < NWG) flags[i] = 0u;
    ((uint_t*)hall)[i] = 0u;                          // 65536 ushorts = 32768 uints (slot 0)
    out[i] = 0.0f;                                    // dummy block 0
    out[32768 + (size_t)BB * SS * AA + i] = 0.0f;     // dummy block 2
}

// ---------------- x_emb gather + bf16 + A-fragment swizzle ----------------
__global__ void k_prep_x(const float* __restrict__ embed, const int* __restrict__ x,
                         ushort_t* __restrict__ xsw) {
    int t = blockIdx.x * 256 + threadIdx.x;          // 4,194,304 threads = [s][kk][rg][lane]
    int lane = t & 63;
    int rg   = (t >> 6) & 3;
    int kk   = (t >> 8) & 31;
    int s    = t >> 13;
    int b  = rg * 16 + (lane & 15);
    int k0 = kk * 32 + (lane >> 4) * 8;
    int tok = x[b * SS + s];
    const float* src = embed + (size_t)tok * HH + k0;
    float4v v0 = *(const float4v*)src;
    float4v v1 = *(const float4v*)(src + 4);
    uint_t p0 = (uint_t)f2bf(v0[0]) | ((uint_t)f2bf(v0[1]) << 16);
    uint_t p1 = (uint_t)f2bf(v0[2]) | ((uint_t)f2bf(v0[3]) << 16);
    uint_t p2 = (uint_t)f2bf(v1[0]) | ((uint_t)f2bf(v1[1]) << 16);
    uint_t p3 = (uint_t)f2bf(v1[2]) | ((uint_t)f2bf(v1[3]) << 16);
    uint4v pk = {p0, p1, p2, p3};
    ((uint4v*)xsw)[t] = pk;
}

// ---------------- [Wi;Wh] -> bf16, gate-interleaved cols, B-fragment swizzle ----------------
__global__ void k_prep_w(const float* __restrict__ Wi, const float* __restrict__ Wh,
                         ushort_t* __restrict__ wsw) {
    int t = blockIdx.x * 256 + threadIdx.x;          // 8,388,608 threads = [k][q][u]
    int u = t & 1023;
    int q = (t >> 10) & 3;
    int k = t >> 12;                                 // 0..2047
    float v = (k < 1024) ? Wi[(size_t)k * 4096 + q * 1024 + u]
                         : Wh[(size_t)(k - 1024) * 4096 + q * 1024 + u];
    int g = u >> 2, du = u & 3;
    int c = du * 4 + q;                              // col-in-slice 0..15
    int kk = k >> 5, quad = (k >> 3) & 3, j = k & 7;
    int lane = quad * 16 + c;
    wsw[(((size_t)g * 64 + kk) * 64 + lane) * 8 + j] = f2bf(v);
}

// ---------------- persistent sequential LSTM scan (v1 schedule, 2 col-tiles/WG) ----------------
__global__ void __launch_bounds__(256)
k_lstm(const ushort_t* __restrict__ xsw, const ushort_t* __restrict__ wsw,
       ushort_t* hall, const float* __restrict__ bh, uint_t* flags) {
    __shared__ ushort_t wlds[2 * 64 * 64 * 8];       // 128 KiB: two slices -> 1 WG/CU guaranteed
    const int g    = blockIdx.x;                     // 0..127, owns slices {2g, 2g+1}
    const int tid  = threadIdx.x;
    const int lane = tid & 63;
    const int rg   = tid >> 6;                       // wave id = batch row-group

    {   // stage both weight slices (contiguous in wsw; coalesced 16B/lane)
        const uint4v* src = (const uint4v*)(wsw + (size_t)(2 * g) * 64 * 64 * 8);
        uint4v* dst = (uint4v*)wlds;
        for (int i = tid; i < 8192; i += 256) dst[i] = src[i];
    }
    __syncthreads();

    const int c_idx = lane & 15;
    const int q  = c_idx & 3;                        // gate (i,f,g,o)
    const int du = c_idx >> 2;                       // unit-within-slice
    const int quad = lane >> 4;
    const float bhv0 = bh[q * 1024 + (2 * g)     * 4 + du];
    const float bhv1 = bh[q * 1024 + (2 * g + 1) * 4 + du];

    uint_t* hall32 = (uint_t*)hall;
    const short8* xbase = (const short8*)xsw;
    const short8* hbase = (const short8*)hall;
    const short8* wl = (const short8*)wlds + lane;   // tile1 weights at +4096 short8

    float cst[2][4];
    #pragma unroll
    for (int t = 0; t < 2; ++t)
        #pragma unroll
        for (int r = 0; r < 4; ++r) cst[t][r] = 0.f;

    for (int s = 0; s < SS; ++s) {
        float4v t0a0 = {bhv0, bhv0, bhv0, bhv0};
        float4v t0a1 = {0.f, 0.f, 0.f, 0.f};
        float4v t0a2 = {0.f, 0.f, 0.f, 0.f};
        float4v t0a3 = {0.f, 0.f, 0.f, 0.f};
        float4v t1a0 = {bhv1, bhv1, bhv1, bhv1};
        float4v t1a1 = {0.f, 0.f, 0.f, 0.f};
        float4v t1a2 = {0.f, 0.f, 0.f, 0.f};
        float4v t1a3 = {0.f, 0.f, 0.f, 0.f};

        // ---- x-part (no dependency on h): overlaps the flag wait below ----
        const short8* xp = xbase + (((size_t)s * 32) * 4 + rg) * 64 + lane;
        #pragma unroll
        for (int kk = 0; kk < 32; kk += 4) {
            short8 a0 = xp[(kk + 0) * 256];
            short8 a1 = xp[(kk + 1) * 256];
            short8 a2 = xp[(kk + 2) * 256];
            short8 a3 = xp[(kk + 3) * 256];
            t0a0 = MFMA(a0, wl[(kk + 0) * 64], t0a0, 0, 0, 0);
            t1a0 = MFMA(a0, wl[4096 + (kk + 0) * 64], t1a0, 0, 0, 0);
            t0a1 = MFMA(a1, wl[(kk + 1) * 64], t0a1, 0, 0, 0);
            t1a1 = MFMA(a1, wl[4096 + (kk + 1) * 64], t1a1, 0, 0, 0);
            t0a2 = MFMA(a2, wl[(kk + 2) * 64], t0a2, 0, 0, 0);
            t1a2 = MFMA(a2, wl[4096 + (kk + 2) * 64], t1a2, 0, 0, 0);
            t0a3 = MFMA(a3, wl[(kk + 3) * 64], t0a3, 0, 0, 0);
            t1a3 = MFMA(a3, wl[4096 + (kk + 3) * 64], t1a3, 0, 0, 0);
        }

        // ---- wait until all WGs finished step s-1 (flags monotone, v1 mechanism) ----
        {
            bool ok;
            do {
                uint_t f = __hip_atomic_load(&flags[tid & (NWG - 1)], __ATOMIC_RELAXED,
                                             __HIP_MEMORY_SCOPE_AGENT);
                ok = (f >= (uint_t)s);
            } while (!__syncthreads_and(ok));
            asm volatile("" ::: "memory");   // no fence: h-writes traveled via sc1 (LLC)
        }

        // ---- h-part (normal cached loads; slot s is write-once, no stale copies) ----
        const short8* hp = hbase + (((size_t)s * 32) * 4 + rg) * 64 + lane;
        #pragma unroll
        for (int kk = 0; kk < 32; kk += 4) {
            short8 a0 = hp[(kk + 0) * 256];
            short8 a1 = hp[(kk + 1) * 256];
            short8 a2 = hp[(kk + 2) * 256];
            short8 a3 = hp[(kk + 3) * 256];
            t0a0 = MFMA(a0, wl[(32 + kk + 0) * 64], t0a0, 0, 0, 0);
            t1a0 = MFMA(a0, wl[4096 + (32 + kk + 0) * 64], t1a0, 0, 0, 0);
            t0a1 = MFMA(a1, wl[(32 + kk + 1) * 64], t0a1, 0, 0, 0);
            t1a1 = MFMA(a1, wl[4096 + (32 + kk + 1) * 64], t1a1, 0, 0, 0);
            t0a2 = MFMA(a2, wl[(32 + kk + 2) * 64], t0a2, 0, 0, 0);
            t1a2 = MFMA(a2, wl[4096 + (32 + kk + 2) * 64], t1a2, 0, 0, 0);
            t0a3 = MFMA(a3, wl[(32 + kk + 3) * 64], t0a3, 0, 0, 0);
            t1a3 = MFMA(a3, wl[4096 + (32 + kk + 3) * 64], t1a3, 0, 0, 0);
        }
        float4v acc0 = (t0a0 + t0a1) + (t0a2 + t0a3);
        float4v acc1 = (t1a0 + t1a1) + (t1a2 + t1a3);

        // ---- elementwise LSTM update per tile: activate own gate, shuffle activated ----
        float hv[2][4];
        #pragma unroll
        for (int t = 0; t < 2; ++t) {
            #pragma unroll
            for (int r = 0; r < 4; ++r) {
                float own = t ? acc1[r] : acc0[r];
                float a = (q == 2) ? fast_tanh(own) : fast_sigmoid(own);
                float x1 = __shfl_xor(a, 1);
                float x2 = __shfl_xor(a, 2);
                float x3 = __shfl_xor(a, 3);
                float gi, gf, gg, go;
                if      (q == 0) { gi = a;  gf = x1; gg = x2; go = x3; }
                else if (q == 1) { gi = x1; gf = a;  gg = x3; go = x2; }
                else if (q == 2) { gi = x2; gf = x3; gg = a;  go = x1; }
                else             { gi = x3; gf = x2; gg = x1; go = a;  }
                float cv = gf * cst[t][r] + gi * gg;
                cst[t][r] = cv;
                hv[t][r] = go * fast_tanh(cv);
            }
        }

        // ---- pack (even u, odd u) bf16 pair -> one dword sc1 store to LLC, per tile ----
        #pragma unroll
        for (int t = 0; t < 2; ++t) {
            float p0 = __shfl_xor(hv[t][0], 4);
            float p1 = __shfl_xor(hv[t][1], 4);
            float p2 = __shfl_xor(hv[t][2], 4);
            float p3 = __shfl_xor(hv[t][3], 4);
            if (q == 0 && (du & 1) == 0) {
                int u = (2 * g + t) * 4 + du;
                int kk_h = u >> 5, quad_h = (u & 31) >> 3, j_h = u & 7;   // j_h even
                size_t base = (((size_t)(s + 1) * 32 + kk_h) * 4 + rg) * 64;
                float pv[4] = {p0, p1, p2, p3};
                #pragma unroll
                for (int r = 0; r < 4; ++r) {
                    uint_t packed = (uint_t)f2bf(hv[t][r]) | ((uint_t)f2bf(pv[r]) << 16);
                    int lane_h = quad_h * 16 + quad * 4 + r;
                    size_t idx = ((base + (size_t)lane_h) * 8 + j_h) >> 1;
                    __hip_atomic_store(&hall32[idx], packed, __ATOMIC_RELAXED,
                                       __HIP_MEMORY_SCOPE_AGENT);
                }
            }
        }
        // __syncthreads drains vmcnt(0) for ALL waves (HW release), then post flag
        __syncthreads();
        if (tid == 0)
            __hip_atomic_store(&flags[g], (uint_t)(s + 1), __ATOMIC_RELAXED,
                               __HIP_MEMORY_SCOPE_AGENT);
    }
}

// ---------------- head GEMM: logits[b][s][:] = h_s @ Wo + bo ----------------
__global__ void __launch_bounds__(256)
k_head(const ushort_t* __restrict__ hall, const float* __restrict__ Wo,
       const float* __restrict__ bo, float* __restrict__ out) {
    __shared__ ushort_t wlds[32 * 2 * 64 * 8];       // 64 KiB: [kk][nt][lane][j]
    const int wg = blockIdx.x;                       // 512 WGs: cg(4) x sg(128)
    const int cg = wg & 3, sg = wg >> 2;
    const int tid = threadIdx.x, lane = tid & 63, rg = tid >> 6;
    const int col0 = cg * 32;

    for (int i = tid; i < 32768; i += 256) {         // [k][col] -> B-frag swizzle
        int k = i >> 5;
        int col = i & 31;
        float v = Wo[(size_t)k * AA + col0 + col];
        int kk = k >> 5, quad = (k >> 3) & 3, j = k & 7;
        int nt = col >> 4, cl = col & 15;
        wlds[(((kk * 2 + nt) * 64) + quad * 16 + cl) * 8 + j] = f2bf(v);
    }
    __syncthreads();

    const int cl = lane & 15, quad = lane >> 4;
    const float bo0 = bo[col0 + cl];
    const float bo1 = bo[col0 + 16 + cl];
    const short8* wl = (const short8*)wlds + lane;

    for (int si = 0; si < 4; ++si) {
        int s = sg * 4 + si;
        float4v a0 = {bo0, bo0, bo0, bo0};
        float4v a1 = {bo1, bo1, bo1, bo1};
        const short8* hp = (const short8*)hall + (((size_t)(s + 1) * 32) * 4 + rg) * 64 + lane;
        #pragma unroll 8
        for (int kk = 0; kk < 32; ++kk) {
            short8 a = hp[kk * 256];
            a0 = MFMA(a, wl[(kk * 2 + 0) * 64], a0, 0, 0, 0);
            a1 = MFMA(a, wl[(kk * 2 + 1) * 64], a1, 0, 0, 0);
        }
        #pragma unroll
        for (int r = 0; r < 4; ++r) {
            int b = rg * 16 + quad * 4 + r;
            size_t o = 32768 + ((size_t)b * SS + s) * AA;
            out[o + col0 + cl]      = a0[r];
            out[o + col0 + 16 + cl] = a1[r];
        }
    }
}

extern "C" void kernel_launch(void* const* d_in, const int* in_sizes, int n_in,
                              void* d_out, int out_size, void* d_ws, size_t ws_size,
                              hipStream_t stream) {
    const float* embed = (const float*)d_in[0];
    const float* Wi    = (const float*)d_in[1];
    const float* Wh    = (const float*)d_in[2];
    const float* bh    = (const float*)d_in[3];
    const float* Wo    = (const float*)d_in[4];
    const float* bo    = (const float*)d_in[5];
    const int*   x     = (const int*)d_in[6];
    float* out = (float*)d_out;
    unsigned char* ws = (unsigned char*)d_ws;

    ushort_t* xsw  = (ushort_t*)(ws + XSW_OFF);
    ushort_t* wsw  = (ushort_t*)(ws + WSW_OFF);
    ushort_t* hall = (ushort_t*)(ws + HALL_OFF);
    uint_t*   flags = (uint_t*)(ws + FLAGS_OFF);

    k_init  <<<128,   256, 0, stream>>>(flags, hall, out);
    k_prep_x<<<16384, 256, 0, stream>>>(embed, x, xsw);
    k_prep_w<<<32768, 256, 0, stream>>>(Wi, Wh, wsw);
    k_lstm  <<<NWG,   256, 0, stream>>>(xsw, wsw, hall, bh, flags);
    k_head  <<<512,   256, 0, stream>>>(hall, Wo, bo, out);
}